// Round 9
// baseline (626.518 us; speedup 1.0000x reference)
//
#include <hip/hip_runtime.h>

#define N_NODES 50000
#define N_EDGES 1600000
#define R_WAV 4
#define D 128
#define NB 391                 // ceil(50000/128) buckets of 128 rows
#define CHUNK 4096             // edges per hist/partition block
#define NPBLK ((N_EDGES + CHUNK - 1) / CHUNK)   // 391
#define MAXB 4800              // bucket capacity for LDS sort (mean 4092, sigma 64)
#define RP_STRIDE 50016        // ints per row_ptr array (>= N+1), batched layout

typedef unsigned int u32;
typedef unsigned short u16;
typedef u32   __attribute__((ext_vector_type(2))) u32x2;
typedef float __attribute__((ext_vector_type(4))) f32x4;

// fp32 -> bf16 bits, round-to-nearest-even
static __device__ inline u16 f2bf(float f) {
    u32 u = __float_as_uint(f);
    u = (u + 0x7FFFu + ((u >> 16) & 1u)) >> 16;
    return (u16)u;
}
static __device__ inline float bf_lo(u32 u) { return __uint_as_float(u << 16); }
static __device__ inline float bf_hi(u32 u) { return __uint_as_float(u & 0xFFFF0000u); }

// ---------------- GEMM: h = x @ W, bf16 row-major [N][128] -------------------
// 16 rows/block, 512 threads = 4 channel-groups of 128. x staged in LDS and
// read via broadcast (round-8 proven: 110us -> ~20us). Bit-identical h.
__global__ __launch_bounds__(512) void gemm_xw(const float* __restrict__ x,
                                               const float* __restrict__ W,
                                               u16* __restrict__ h) {
    __shared__ float xs[16 * 128];
    const int tid = threadIdx.x;
    const int j = tid & 127;          // output channel
    const int g = tid >> 7;           // row group: rows 4g..4g+3
    const int row0 = blockIdx.x * 16;
    for (int t = tid; t < 16 * 128; t += 512) xs[t] = x[(size_t)row0 * D + t];
    __syncthreads();
    const float* xg = xs + g * 512;
    float a0 = 0.f, a1 = 0.f, a2 = 0.f, a3 = 0.f;
#pragma unroll 8
    for (int k = 0; k < 128; ++k) {
        const float w = W[k * D + j];
        a0 += xg[k] * w;
        a1 += xg[128 + k] * w;
        a2 += xg[256 + k] * w;
        a3 += xg[384 + k] * w;
    }
    const int r0 = row0 + 4 * g;
    h[(size_t)(r0 + 0) * D + j] = f2bf(a0);
    h[(size_t)(r0 + 1) * D + j] = f2bf(a1);
    h[(size_t)(r0 + 2) * D + j] = f2bf(a2);
    h[(size_t)(r0 + 3) * D + j] = f2bf(a3);
}

// ------ hist: per-chunk bucket histogram (saved for partition+scan) ----------
__global__ __launch_bounds__(256) void bucket_hist_all(const int* __restrict__ rows_all,
                                                       int* __restrict__ hist) {
    __shared__ int lh[NB];
    const int r = blockIdx.y;
    const int* rows = rows_all + (size_t)r * N_EDGES;
    const int tid = threadIdx.x;
    for (int i = tid; i < NB; i += 256) lh[i] = 0;
    __syncthreads();
    const int e0 = blockIdx.x * CHUNK;
    const int e1 = min(e0 + CHUNK, N_EDGES);
    for (int i = e0 + tid; i < e1; i += 256) atomicAdd(&lh[rows[i] >> 7], 1);
    __syncthreads();
    int* hc = hist + ((size_t)r * NPBLK + blockIdx.x) * NB;
    for (int i = tid; i < NB; i += 256) hc[i] = lh[i];
}

// ------ chunk_scan: per-bucket exclusive prefix over chunks + totals ---------
__global__ __launch_bounds__(512) void chunk_scan(const int* __restrict__ hist,
                                                  int* __restrict__ chunkpre,
                                                  int* __restrict__ cnt) {
    __shared__ int sa[512], sb[512];
    const int b = blockIdx.x;
    const int r = blockIdx.y;
    const int tid = threadIdx.x;
    const int v = (tid < NPBLK) ? hist[((size_t)r * NPBLK + tid) * NB + b] : 0;
    sa[tid] = v;
    int* cur = sa;
    int* nxt = sb;
    for (int d = 1; d < 512; d <<= 1) {
        __syncthreads();
        int t = cur[tid];
        if (tid >= d) t += cur[tid - d];
        nxt[tid] = t;
        int* tmp = cur; cur = nxt; nxt = tmp;
    }
    __syncthreads();
    const int excl = cur[tid] - v;
    if (tid < NPBLK) chunkpre[((size_t)r * NPBLK + tid) * NB + b] = excl;
    if (tid == NPBLK - 1) cnt[r * NB + b] = excl + v;
}

// ------------- batched scan of bucket counts: grid R_WAV ---------------------
__global__ __launch_bounds__(512) void scan_buckets_all(const int* __restrict__ cnt4,
                                                        int* __restrict__ bptr4) {
    __shared__ int sa[512], sb[512];
    const int r = blockIdx.x;
    const int* cnt = cnt4 + r * NB;
    int* bptr = bptr4 + r * (NB + 1);
    const int tid = threadIdx.x;
    const int v = (tid < NB) ? cnt[tid] : 0;
    sa[tid] = v;
    int* cur = sa;
    int* nxt = sb;
    for (int d = 1; d < 512; d <<= 1) {
        __syncthreads();
        int t = cur[tid];
        if (tid >= d) t += cur[tid - d];
        nxt[tid] = t;
        int* tmp = cur; cur = nxt; nxt = tmp;
    }
    __syncthreads();
    const int excl = cur[tid] - v;
    if (tid <= NB) bptr[tid] = excl;
}

// ---------------- partition: single edge pass, deterministic bases -----------
// Emits slim payload: cvA = packed {bf16(val):hi16, col:lo16} (the FINAL cv4
// word) + rowloc = u16 row id. (round-3 proven)
__global__ __launch_bounds__(256) void partition_kernel(const int* __restrict__ rows,
                                                        const int* __restrict__ cols,
                                                        const float* __restrict__ vals,
                                                        const int* __restrict__ bptr_all,
                                                        const int* __restrict__ chunkpre,
                                                        const int* __restrict__ hist,
                                                        u32* __restrict__ cvA,
                                                        u16* __restrict__ rowloc) {
    const int r = blockIdx.y;
    rows   += (size_t)r * N_EDGES;
    cols   += (size_t)r * N_EDGES;
    vals   += (size_t)r * N_EDGES;
    cvA    += (size_t)r * N_EDGES;
    rowloc += (size_t)r * N_EDGES;
    const int* bptr = bptr_all + r * (NB + 1);
    const int* hc   = hist     + ((size_t)r * NPBLK + blockIdx.x) * NB;
    const int* cp   = chunkpre + ((size_t)r * NPBLK + blockIdx.x) * NB;
    __shared__ int lh[NB], lptr[NB], lcur[NB], lbase[NB];
    __shared__ int sa[256], sb[256];
    __shared__ u32 st_cv[CHUNK];
    __shared__ u16 st_rl[CHUNK];
    const int tid = threadIdx.x;
    for (int i = tid; i < NB; i += 256) lh[i] = hc[i];
    __syncthreads();
    const int e0 = blockIdx.x * CHUNK;
    const int e1 = min(e0 + CHUNK, N_EDGES);
    const int cnt = e1 - e0;
    const int p0 = (2 * tid < NB) ? lh[2 * tid] : 0;
    const int p1 = (2 * tid + 1 < NB) ? lh[2 * tid + 1] : 0;
    sa[tid] = p0 + p1;
    int* cur = sa;
    int* nxt = sb;
    for (int d = 1; d < 256; d <<= 1) {
        __syncthreads();
        int t = cur[tid];
        if (tid >= d) t += cur[tid - d];
        nxt[tid] = t;
        int* tmp = cur; cur = nxt; nxt = tmp;
    }
    __syncthreads();
    const int pe = cur[tid] - (p0 + p1);
    if (2 * tid < NB)     { lptr[2 * tid] = pe;           lcur[2 * tid] = pe; }
    if (2 * tid + 1 < NB) { lptr[2 * tid + 1] = pe + p0;  lcur[2 * tid + 1] = pe + p0; }
    __syncthreads();
    for (int i = e0 + tid; i < e1; i += 256) {
        const int row = rows[i];
        const int b = row >> 7;
        const int pos = atomicAdd(&lcur[b], 1);
        st_cv[pos] = ((u32)f2bf(vals[i]) << 16) | ((u32)cols[i] & 0xFFFFu);
        st_rl[pos] = (u16)row;
    }
    for (int b = tid; b < NB; b += 256) lbase[b] = bptr[b] + cp[b] - lptr[b];
    __syncthreads();
    for (int i = tid; i < cnt; i += 256) {
        const u16 rl = st_rl[i];
        const int b = (int)rl >> 7;
        const int o = lbase[b] + i;
        cvA[o] = st_cv[i];
        rowloc[o] = rl;
    }
}

// ------- per-bucket CSR: 128-bin counting sort of pre-packed 4B edges --------
__global__ __launch_bounds__(256) void bucket_csr(const int* __restrict__ bptr_all,
                                                  const u32* __restrict__ cvA,
                                                  const u16* __restrict__ rowloc,
                                                  u32* __restrict__ cv4,
                                                  int* __restrict__ row_ptr) {
    const int r = blockIdx.y;
    const int* bptr = bptr_all + r * (NB + 1);
    cvA     += (size_t)r * N_EDGES;
    rowloc  += (size_t)r * N_EDGES;
    cv4     += (size_t)r * N_EDGES;
    row_ptr += r * RP_STRIDE;
    __shared__ int lh[128], lexcl[128], lcur[128];
    __shared__ u32 st[MAXB];
    const int b = blockIdx.x;
    const int s = bptr[b], e1 = bptr[b + 1];
    const int cnt = e1 - s;
    const int tid = threadIdx.x;
    if (tid < 128) lh[tid] = 0;
    __syncthreads();
    for (int i = s + tid; i < e1; i += 256)
        atomicAdd(&lh[(int)rowloc[i] & 127], 1);
    __syncthreads();
    if (tid < 64) {
        const int p0 = lh[2 * tid], p1 = lh[2 * tid + 1];
        int ssum = p0 + p1;
#pragma unroll
        for (int d = 1; d < 64; d <<= 1) {
            const int t = __shfl_up(ssum, d, 64);
            if (tid >= d) ssum += t;
        }
        const int pe = ssum - (p0 + p1);
        lexcl[2 * tid] = pe;          lcur[2 * tid] = pe;
        lexcl[2 * tid + 1] = pe + p0; lcur[2 * tid + 1] = pe + p0;
    }
    __syncthreads();
    for (int i = s + tid; i < e1; i += 256) {
        const int lr = (int)rowloc[i] & 127;
        const int pos = atomicAdd(&lcur[lr], 1);
        if (pos < MAXB) st[pos] = cvA[i];
    }
    __syncthreads();
    const int wb = (cnt < MAXB) ? cnt : MAXB;
    for (int i = tid; i < wb; i += 256) cv4[s + i] = st[i];
    if (tid < 128) {
        const int row = (b << 7) + tid;
        if (row < N_NODES) row_ptr[row] = s + lexcl[tid];
    }
    if (blockIdx.x == 0 && tid == 0) row_ptr[N_NODES] = N_EDGES;
}

// ---------------- SpMM pass 1: y = bf16( filt * (A @ h) ) --------------------
// Round-3 gather scheme. NEW: cv4 edge-word loads and y2 stores are
// NONTEMPORAL -- both are single-use streams whose L2 write-allocate/retention
// was evicting the h gather target (capacity misses = the whole 165us).
__global__ __launch_bounds__(256) void spmm1(const int* __restrict__ row_ptr,
                                             const u32* __restrict__ cvp,
                                             const u32* __restrict__ h2,
                                             const float* __restrict__ filt,
                                             u32* __restrict__ y2) {
    const int r = blockIdx.y;
    row_ptr += r * RP_STRIDE;
    cvp     += (size_t)r * N_EDGES;
    filt    += (size_t)r * N_NODES;
    y2      += (size_t)r * (N_NODES * 64);
    const int row = __builtin_amdgcn_readfirstlane(blockIdx.x * 4 + (threadIdx.x >> 6));
    const int lane = threadIdx.x & 63;
    const int half = lane >> 5;
    const int l = lane & 31;
    int e = row_ptr[row];
    const int end = row_ptr[row + 1];
    float a0 = 0.f, a1 = 0.f, a2 = 0.f, a3 = 0.f;
    float b0 = 0.f, b1 = 0.f, b2 = 0.f, b3 = 0.f;
    for (; e + 16 <= end; e += 16) {
        u32 c[16];
#pragma unroll
        for (int i = 0; i < 16; ++i) c[i] = __builtin_nontemporal_load(&cvp[e + i]);
        const u32 u0 = half ? c[1] : c[0];
        const u32 u1 = half ? c[3] : c[2];
        const u32 u2 = half ? c[5] : c[4];
        const u32 u3 = half ? c[7] : c[6];
        const u32 u4 = half ? c[9] : c[8];
        const u32 u5 = half ? c[11] : c[10];
        const u32 u6 = half ? c[13] : c[12];
        const u32 u7 = half ? c[15] : c[14];
        const uint2 g0 = *(const uint2*)(h2 + (u0 & 0xFFFFu) * 64 + 2 * l);
        const uint2 g1 = *(const uint2*)(h2 + (u1 & 0xFFFFu) * 64 + 2 * l);
        const uint2 g2 = *(const uint2*)(h2 + (u2 & 0xFFFFu) * 64 + 2 * l);
        const uint2 g3 = *(const uint2*)(h2 + (u3 & 0xFFFFu) * 64 + 2 * l);
        const uint2 g4 = *(const uint2*)(h2 + (u4 & 0xFFFFu) * 64 + 2 * l);
        const uint2 g5 = *(const uint2*)(h2 + (u5 & 0xFFFFu) * 64 + 2 * l);
        const uint2 g6 = *(const uint2*)(h2 + (u6 & 0xFFFFu) * 64 + 2 * l);
        const uint2 g7 = *(const uint2*)(h2 + (u7 & 0xFFFFu) * 64 + 2 * l);
        const float v0 = __uint_as_float(u0 & 0xFFFF0000u);
        const float v1 = __uint_as_float(u1 & 0xFFFF0000u);
        const float v2 = __uint_as_float(u2 & 0xFFFF0000u);
        const float v3 = __uint_as_float(u3 & 0xFFFF0000u);
        const float v4 = __uint_as_float(u4 & 0xFFFF0000u);
        const float v5 = __uint_as_float(u5 & 0xFFFF0000u);
        const float v6 = __uint_as_float(u6 & 0xFFFF0000u);
        const float v7 = __uint_as_float(u7 & 0xFFFF0000u);
        a0 += v0 * bf_lo(g0.x); a1 += v0 * bf_hi(g0.x);
        a2 += v0 * bf_lo(g0.y); a3 += v0 * bf_hi(g0.y);
        b0 += v1 * bf_lo(g1.x); b1 += v1 * bf_hi(g1.x);
        b2 += v1 * bf_lo(g1.y); b3 += v1 * bf_hi(g1.y);
        a0 += v2 * bf_lo(g2.x); a1 += v2 * bf_hi(g2.x);
        a2 += v2 * bf_lo(g2.y); a3 += v2 * bf_hi(g2.y);
        b0 += v3 * bf_lo(g3.x); b1 += v3 * bf_hi(g3.x);
        b2 += v3 * bf_lo(g3.y); b3 += v3 * bf_hi(g3.y);
        a0 += v4 * bf_lo(g4.x); a1 += v4 * bf_hi(g4.x);
        a2 += v4 * bf_lo(g4.y); a3 += v4 * bf_hi(g4.y);
        b0 += v5 * bf_lo(g5.x); b1 += v5 * bf_hi(g5.x);
        b2 += v5 * bf_lo(g5.y); b3 += v5 * bf_hi(g5.y);
        a0 += v6 * bf_lo(g6.x); a1 += v6 * bf_hi(g6.x);
        a2 += v6 * bf_lo(g6.y); a3 += v6 * bf_hi(g6.y);
        b0 += v7 * bf_lo(g7.x); b1 += v7 * bf_hi(g7.x);
        b2 += v7 * bf_lo(g7.y); b3 += v7 * bf_hi(g7.y);
    }
    for (; e + 8 <= end; e += 8) {
        const u32 c0 = __builtin_nontemporal_load(&cvp[e]);
        const u32 c1 = __builtin_nontemporal_load(&cvp[e + 1]);
        const u32 c2 = __builtin_nontemporal_load(&cvp[e + 2]);
        const u32 c3 = __builtin_nontemporal_load(&cvp[e + 3]);
        const u32 c4 = __builtin_nontemporal_load(&cvp[e + 4]);
        const u32 c5 = __builtin_nontemporal_load(&cvp[e + 5]);
        const u32 c6 = __builtin_nontemporal_load(&cvp[e + 6]);
        const u32 c7 = __builtin_nontemporal_load(&cvp[e + 7]);
        const u32 uA = half ? c1 : c0;
        const u32 uB = half ? c3 : c2;
        const u32 uC = half ? c5 : c4;
        const u32 uD = half ? c7 : c6;
        const uint2 gA = *(const uint2*)(h2 + (uA & 0xFFFFu) * 64 + 2 * l);
        const uint2 gB = *(const uint2*)(h2 + (uB & 0xFFFFu) * 64 + 2 * l);
        const uint2 gC = *(const uint2*)(h2 + (uC & 0xFFFFu) * 64 + 2 * l);
        const uint2 gD = *(const uint2*)(h2 + (uD & 0xFFFFu) * 64 + 2 * l);
        const float vA = __uint_as_float(uA & 0xFFFF0000u);
        const float vB = __uint_as_float(uB & 0xFFFF0000u);
        const float vC = __uint_as_float(uC & 0xFFFF0000u);
        const float vD = __uint_as_float(uD & 0xFFFF0000u);
        a0 += vA * bf_lo(gA.x); a1 += vA * bf_hi(gA.x);
        a2 += vA * bf_lo(gA.y); a3 += vA * bf_hi(gA.y);
        b0 += vB * bf_lo(gB.x); b1 += vB * bf_hi(gB.x);
        b2 += vB * bf_lo(gB.y); b3 += vB * bf_hi(gB.y);
        a0 += vC * bf_lo(gC.x); a1 += vC * bf_hi(gC.x);
        a2 += vC * bf_lo(gC.y); a3 += vC * bf_hi(gC.y);
        b0 += vD * bf_lo(gD.x); b1 += vD * bf_hi(gD.x);
        b2 += vD * bf_lo(gD.y); b3 += vD * bf_hi(gD.y);
    }
    for (; e < end; e += 2) {
        const u32 c0 = __builtin_nontemporal_load(&cvp[e]);
        const u32 c1 = (e + 1 < end) ? __builtin_nontemporal_load(&cvp[e + 1]) : 0u;
        const u32 uA = half ? c1 : c0;
        const uint2 gA = *(const uint2*)(h2 + (uA & 0xFFFFu) * 64 + 2 * l);
        const float vA = __uint_as_float(uA & 0xFFFF0000u);
        a0 += vA * bf_lo(gA.x); a1 += vA * bf_hi(gA.x);
        a2 += vA * bf_lo(gA.y); a3 += vA * bf_hi(gA.y);
    }
    a0 += b0; a1 += b1; a2 += b2; a3 += b3;
    a0 += __shfl_xor(a0, 32, 64);
    a1 += __shfl_xor(a1, 32, 64);
    a2 += __shfl_xor(a2, 32, 64);
    a3 += __shfl_xor(a3, 32, 64);
    const float f = filt[row];
    if (half == 0) {
        u32x2 o;
        o.x = (u32)f2bf(f * a0) | ((u32)f2bf(f * a1) << 16);
        o.y = (u32)f2bf(f * a2) | ((u32)f2bf(f * a3) << 16);
        __builtin_nontemporal_store(o, (u32x2*)(y2 + (size_t)row * 64 + 2 * l));
    }
}

// ---------------- SpMM pass 2 (per-r) ----------------------------------------
// cv4 loads + out RMW are nontemporal streams; y2 gathers keep L2 priority.
template <bool FIRST>
__global__ __launch_bounds__(256) void spmm2(const int* __restrict__ row_ptr,
                                             const u32* __restrict__ cvp,
                                             const u32* __restrict__ y2,
                                             const float* __restrict__ bias,
                                             float* __restrict__ out) {
    const int row = __builtin_amdgcn_readfirstlane(blockIdx.x * 4 + (threadIdx.x >> 6));
    const int lane = threadIdx.x & 63;
    const int half = lane >> 5;
    const int l = lane & 31;
    int e = row_ptr[row];
    const int end = row_ptr[row + 1];
    float a0 = 0.f, a1 = 0.f, a2 = 0.f, a3 = 0.f;
    float b0 = 0.f, b1 = 0.f, b2 = 0.f, b3 = 0.f;
    for (; e + 16 <= end; e += 16) {
        u32 c[16];
#pragma unroll
        for (int i = 0; i < 16; ++i) c[i] = __builtin_nontemporal_load(&cvp[e + i]);
        const u32 u0 = half ? c[1] : c[0];
        const u32 u1 = half ? c[3] : c[2];
        const u32 u2 = half ? c[5] : c[4];
        const u32 u3 = half ? c[7] : c[6];
        const u32 u4 = half ? c[9] : c[8];
        const u32 u5 = half ? c[11] : c[10];
        const u32 u6 = half ? c[13] : c[12];
        const u32 u7 = half ? c[15] : c[14];
        const uint2 g0 = *(const uint2*)(y2 + (u0 & 0xFFFFu) * 64 + 2 * l);
        const uint2 g1 = *(const uint2*)(y2 + (u1 & 0xFFFFu) * 64 + 2 * l);
        const uint2 g2 = *(const uint2*)(y2 + (u2 & 0xFFFFu) * 64 + 2 * l);
        const uint2 g3 = *(const uint2*)(y2 + (u3 & 0xFFFFu) * 64 + 2 * l);
        const uint2 g4 = *(const uint2*)(y2 + (u4 & 0xFFFFu) * 64 + 2 * l);
        const uint2 g5 = *(const uint2*)(y2 + (u5 & 0xFFFFu) * 64 + 2 * l);
        const uint2 g6 = *(const uint2*)(y2 + (u6 & 0xFFFFu) * 64 + 2 * l);
        const uint2 g7 = *(const uint2*)(y2 + (u7 & 0xFFFFu) * 64 + 2 * l);
        const float v0 = __uint_as_float(u0 & 0xFFFF0000u);
        const float v1 = __uint_as_float(u1 & 0xFFFF0000u);
        const float v2 = __uint_as_float(u2 & 0xFFFF0000u);
        const float v3 = __uint_as_float(u3 & 0xFFFF0000u);
        const float v4 = __uint_as_float(u4 & 0xFFFF0000u);
        const float v5 = __uint_as_float(u5 & 0xFFFF0000u);
        const float v6 = __uint_as_float(u6 & 0xFFFF0000u);
        const float v7 = __uint_as_float(u7 & 0xFFFF0000u);
        a0 += v0 * bf_lo(g0.x); a1 += v0 * bf_hi(g0.x);
        a2 += v0 * bf_lo(g0.y); a3 += v0 * bf_hi(g0.y);
        b0 += v1 * bf_lo(g1.x); b1 += v1 * bf_hi(g1.x);
        b2 += v1 * bf_lo(g1.y); b3 += v1 * bf_hi(g1.y);
        a0 += v2 * bf_lo(g2.x); a1 += v2 * bf_hi(g2.x);
        a2 += v2 * bf_lo(g2.y); a3 += v2 * bf_hi(g2.y);
        b0 += v3 * bf_lo(g3.x); b1 += v3 * bf_hi(g3.x);
        b2 += v3 * bf_lo(g3.y); b3 += v3 * bf_hi(g3.y);
        a0 += v4 * bf_lo(g4.x); a1 += v4 * bf_hi(g4.x);
        a2 += v4 * bf_lo(g4.y); a3 += v4 * bf_hi(g4.y);
        b0 += v5 * bf_lo(g5.x); b1 += v5 * bf_hi(g5.x);
        b2 += v5 * bf_lo(g5.y); b3 += v5 * bf_hi(g5.y);
        a0 += v6 * bf_lo(g6.x); a1 += v6 * bf_hi(g6.x);
        a2 += v6 * bf_lo(g6.y); a3 += v6 * bf_hi(g6.y);
        b0 += v7 * bf_lo(g7.x); b1 += v7 * bf_hi(g7.x);
        b2 += v7 * bf_lo(g7.y); b3 += v7 * bf_hi(g7.y);
    }
    for (; e + 8 <= end; e += 8) {
        const u32 c0 = __builtin_nontemporal_load(&cvp[e]);
        const u32 c1 = __builtin_nontemporal_load(&cvp[e + 1]);
        const u32 c2 = __builtin_nontemporal_load(&cvp[e + 2]);
        const u32 c3 = __builtin_nontemporal_load(&cvp[e + 3]);
        const u32 c4 = __builtin_nontemporal_load(&cvp[e + 4]);
        const u32 c5 = __builtin_nontemporal_load(&cvp[e + 5]);
        const u32 c6 = __builtin_nontemporal_load(&cvp[e + 6]);
        const u32 c7 = __builtin_nontemporal_load(&cvp[e + 7]);
        const u32 uA = half ? c1 : c0;
        const u32 uB = half ? c3 : c2;
        const u32 uC = half ? c5 : c4;
        const u32 uD = half ? c7 : c6;
        const uint2 gA = *(const uint2*)(y2 + (uA & 0xFFFFu) * 64 + 2 * l);
        const uint2 gB = *(const uint2*)(y2 + (uB & 0xFFFFu) * 64 + 2 * l);
        const uint2 gC = *(const uint2*)(y2 + (uC & 0xFFFFu) * 64 + 2 * l);
        const uint2 gD = *(const uint2*)(y2 + (uD & 0xFFFFu) * 64 + 2 * l);
        const float vA = __uint_as_float(uA & 0xFFFF0000u);
        const float vB = __uint_as_float(uB & 0xFFFF0000u);
        const float vC = __uint_as_float(uC & 0xFFFF0000u);
        const float vD = __uint_as_float(uD & 0xFFFF0000u);
        a0 += vA * bf_lo(gA.x); a1 += vA * bf_hi(gA.x);
        a2 += vA * bf_lo(gA.y); a3 += vA * bf_hi(gA.y);
        b0 += vB * bf_lo(gB.x); b1 += vB * bf_hi(gB.x);
        b2 += vB * bf_lo(gB.y); b3 += vB * bf_hi(gB.y);
        a0 += vC * bf_lo(gC.x); a1 += vC * bf_hi(gC.x);
        a2 += vC * bf_lo(gC.y); a3 += vC * bf_hi(gC.y);
        b0 += vD * bf_lo(gD.x); b1 += vD * bf_hi(gD.x);
        b2 += vD * bf_lo(gD.y); b3 += vD * bf_hi(gD.y);
    }
    for (; e < end; e += 2) {
        const u32 c0 = __builtin_nontemporal_load(&cvp[e]);
        const u32 c1 = (e + 1 < end) ? __builtin_nontemporal_load(&cvp[e + 1]) : 0u;
        const u32 uA = half ? c1 : c0;
        const uint2 gA = *(const uint2*)(y2 + (uA & 0xFFFFu) * 64 + 2 * l);
        const float vA = __uint_as_float(uA & 0xFFFF0000u);
        a0 += vA * bf_lo(gA.x); a1 += vA * bf_hi(gA.x);
        a2 += vA * bf_lo(gA.y); a3 += vA * bf_hi(gA.y);
    }
    a0 += b0; a1 += b1; a2 += b2; a3 += b3;
    a0 += __shfl_xor(a0, 32, 64);
    a1 += __shfl_xor(a1, 32, 64);
    a2 += __shfl_xor(a2, 32, 64);
    a3 += __shfl_xor(a3, 32, 64);
    if (half == 0) {
        float* op = out + (size_t)row * D + 4 * l;
        if (FIRST) {
            const float4 bb = *(const float4*)(bias + 4 * l);
            f32x4 o = {a0 + bb.x, a1 + bb.y, a2 + bb.z, a3 + bb.w};
            __builtin_nontemporal_store(o, (f32x4*)op);
        } else {
            const f32x4 cc = __builtin_nontemporal_load((const f32x4*)op);
            f32x4 o = {cc.x + a0, cc.y + a1, cc.z + a2, cc.w + a3};
            __builtin_nontemporal_store(o, (f32x4*)op);
        }
    }
}

extern "C" void kernel_launch(void* const* d_in, const int* in_sizes, int n_in,
                              void* d_out, int out_size, void* d_ws, size_t ws_size,
                              hipStream_t stream) {
    const float* x    = (const float*)d_in[0];  // [N,128]
    const float* vals = (const float*)d_in[1];  // [R,E]
    const float* W    = (const float*)d_in[2];  // [128,128]
    const float* filt = (const float*)d_in[3];  // [R*N,1]
    const float* bias = (const float*)d_in[4];  // [128]
    const int*   rows = (const int*)d_in[5];    // [R,E]
    const int*   cols = (const int*)d_in[6];    // [R,E]
    float* out = (float*)d_out;                 // [N,128]

    char* ws = (char*)d_ws;
    // Layout (<= 90,419,968 B, proven available):
    //   [0, 12.8M)        h bf16 [N][128]
    //   [12.8M, 64M)      region B:
    //                       cvA  u32 [R][E]  @ 12.8M   (25.6 MB)
    //                       rowloc u16 [R][E] @ 38.4M  (12.8 MB)
    //                     aliased by y2 bf16 [R][N][128] @ 12.8M (51.2 MB)
    //                     (cvA/rowloc dead before spmm1 writes y2)
    //   [64M, 89.6M)      cv4 u32 [R][E]  (alias: hist+cpre, 4.9 MB, dead
    //                     before bucket_csr writes cv4)
    //   [89.6M, ...)      rp, cnt, bptr
    u16*  h      = (u16*)(ws);
    u32*  cvA    = (u32*)(ws + 12800000);
    u16*  rowloc = (u16*)(ws + 38400000);
    u32*  y2     = (u32*)(ws + 12800000);          // alias of cvA/rowloc
    u32*  cv4    = (u32*)(ws + 64000000);
    int*  hist   = (int*)(ws + 64000000);          // alias of cv4 region
    int*  cpre   = (int*)(ws + 66446096);          // alias of cv4 region
    int*  rp     = (int*)(ws + 89600000);          // 4 x RP_STRIDE ints
    int*  cnt4   = (int*)(ws + 90400512);          // 4*NB ints
    int*  bptr4  = (int*)(ws + 90406768);          // 4*(NB+1) ints

    bucket_hist_all<<<dim3(NPBLK, R_WAV), 256, 0, stream>>>(rows, hist);
    chunk_scan<<<dim3(NB, R_WAV), 512, 0, stream>>>(hist, cpre, cnt4);
    scan_buckets_all<<<R_WAV, 512, 0, stream>>>(cnt4, bptr4);
    partition_kernel<<<dim3(NPBLK, R_WAV), 256, 0, stream>>>(rows, cols, vals,
                                                             bptr4, cpre, hist,
                                                             cvA, rowloc);
    bucket_csr<<<dim3(NB, R_WAV), 256, 0, stream>>>(bptr4, cvA, rowloc, cv4, rp);

    gemm_xw<<<N_NODES / 16, 512, 0, stream>>>(x, W, h);

    spmm1<<<dim3(N_NODES / 4, R_WAV), 256, 0, stream>>>(rp, cv4, (const u32*)h,
                                                        filt, y2);
    for (int r = 0; r < R_WAV; ++r) {
        const int* rp_r  = rp + r * RP_STRIDE;
        const u32* cv4_r = cv4 + (size_t)r * N_EDGES;
        const u32* y2_r  = y2 + (size_t)r * (N_NODES * 64);
        if (r == 0)
            spmm2<true><<<N_NODES / 4, 256, 0, stream>>>(rp_r, cv4_r, y2_r, bias, out);
        else
            spmm2<false><<<N_NODES / 4, 256, 0, stream>>>(rp_r, cv4_r, y2_r, bias, out);
    }
}

// Round 10
// 590.914 us; speedup vs baseline: 1.0603x; 1.0603x over previous
//
#include <hip/hip_runtime.h>

#define N_NODES 50000
#define N_EDGES 1600000
#define R_WAV 4
#define D 128
#define NB 391                 // ceil(50000/128) buckets of 128 rows
#define CHUNK 4096             // edges per hist/partition block
#define NPBLK ((N_EDGES + CHUNK - 1) / CHUNK)   // 391
#define MAXB 4800              // bucket capacity for LDS sort (mean 4092, sigma 64)
#define RP_STRIDE 50016        // ints per row_ptr array (>= N+1), batched layout

typedef unsigned int u32;
typedef unsigned short u16;
typedef u32   __attribute__((ext_vector_type(2))) u32x2;
typedef float __attribute__((ext_vector_type(4))) f32x4;

// fp32 -> bf16 bits, round-to-nearest-even
static __device__ inline u16 f2bf(float f) {
    u32 u = __float_as_uint(f);
    u = (u + 0x7FFFu + ((u >> 16) & 1u)) >> 16;
    return (u16)u;
}
static __device__ inline float bf_lo(u32 u) { return __uint_as_float(u << 16); }
static __device__ inline float bf_hi(u32 u) { return __uint_as_float(u & 0xFFFF0000u); }

// ---------------- GEMM: h = x @ W, bf16 row-major [N][128] -------------------
// 16 rows/block, 512 threads = 4 channel-groups of 128. x staged in LDS and
// read via broadcast (round-8 proven: 110us -> ~20us). Bit-identical h.
__global__ __launch_bounds__(512) void gemm_xw(const float* __restrict__ x,
                                               const float* __restrict__ W,
                                               u16* __restrict__ h) {
    __shared__ float xs[16 * 128];
    const int tid = threadIdx.x;
    const int j = tid & 127;          // output channel
    const int g = tid >> 7;           // row group: rows 4g..4g+3
    const int row0 = blockIdx.x * 16;
    for (int t = tid; t < 16 * 128; t += 512) xs[t] = x[(size_t)row0 * D + t];
    __syncthreads();
    const float* xg = xs + g * 512;
    float a0 = 0.f, a1 = 0.f, a2 = 0.f, a3 = 0.f;
#pragma unroll 8
    for (int k = 0; k < 128; ++k) {
        const float w = W[k * D + j];
        a0 += xg[k] * w;
        a1 += xg[128 + k] * w;
        a2 += xg[256 + k] * w;
        a3 += xg[384 + k] * w;
    }
    const int r0 = row0 + 4 * g;
    h[(size_t)(r0 + 0) * D + j] = f2bf(a0);
    h[(size_t)(r0 + 1) * D + j] = f2bf(a1);
    h[(size_t)(r0 + 2) * D + j] = f2bf(a2);
    h[(size_t)(r0 + 3) * D + j] = f2bf(a3);
}

// ------ hist: per-chunk bucket histogram, int4-vectorized edge reads ---------
// (chunk sizes 4096 / 2560 are both divisible by 4 and 16B-aligned)
__global__ __launch_bounds__(256) void bucket_hist_all(const int* __restrict__ rows_all,
                                                       int* __restrict__ hist) {
    __shared__ int lh[NB];
    const int r = blockIdx.y;
    const int* rows = rows_all + (size_t)r * N_EDGES;
    const int tid = threadIdx.x;
    for (int i = tid; i < NB; i += 256) lh[i] = 0;
    __syncthreads();
    const int e0 = blockIdx.x * CHUNK;
    const int e1 = min(e0 + CHUNK, N_EDGES);
    const int nv = (e1 - e0) >> 2;
    const int4* rows4 = (const int4*)(rows + e0);
    for (int i = tid; i < nv; i += 256) {
        const int4 rr = rows4[i];
        atomicAdd(&lh[rr.x >> 7], 1);
        atomicAdd(&lh[rr.y >> 7], 1);
        atomicAdd(&lh[rr.z >> 7], 1);
        atomicAdd(&lh[rr.w >> 7], 1);
    }
    __syncthreads();
    int* hc = hist + ((size_t)r * NPBLK + blockIdx.x) * NB;
    for (int i = tid; i < NB; i += 256) hc[i] = lh[i];
}

// ------ chunk_scan: per-bucket exclusive prefix over chunks + totals ---------
__global__ __launch_bounds__(512) void chunk_scan(const int* __restrict__ hist,
                                                  int* __restrict__ chunkpre,
                                                  int* __restrict__ cnt) {
    __shared__ int sa[512], sb[512];
    const int b = blockIdx.x;
    const int r = blockIdx.y;
    const int tid = threadIdx.x;
    const int v = (tid < NPBLK) ? hist[((size_t)r * NPBLK + tid) * NB + b] : 0;
    sa[tid] = v;
    int* cur = sa;
    int* nxt = sb;
    for (int d = 1; d < 512; d <<= 1) {
        __syncthreads();
        int t = cur[tid];
        if (tid >= d) t += cur[tid - d];
        nxt[tid] = t;
        int* tmp = cur; cur = nxt; nxt = tmp;
    }
    __syncthreads();
    const int excl = cur[tid] - v;
    if (tid < NPBLK) chunkpre[((size_t)r * NPBLK + tid) * NB + b] = excl;
    if (tid == NPBLK - 1) cnt[r * NB + b] = excl + v;
}

// ------------- batched scan of bucket counts: grid R_WAV ---------------------
__global__ __launch_bounds__(512) void scan_buckets_all(const int* __restrict__ cnt4,
                                                        int* __restrict__ bptr4) {
    __shared__ int sa[512], sb[512];
    const int r = blockIdx.x;
    const int* cnt = cnt4 + r * NB;
    int* bptr = bptr4 + r * (NB + 1);
    const int tid = threadIdx.x;
    const int v = (tid < NB) ? cnt[tid] : 0;
    sa[tid] = v;
    int* cur = sa;
    int* nxt = sb;
    for (int d = 1; d < 512; d <<= 1) {
        __syncthreads();
        int t = cur[tid];
        if (tid >= d) t += cur[tid - d];
        nxt[tid] = t;
        int* tmp = cur; cur = nxt; nxt = tmp;
    }
    __syncthreads();
    const int excl = cur[tid] - v;
    if (tid <= NB) bptr[tid] = excl;
}

// ---------------- partition: int4-vectorized reads, int2 packed output -------
// Emits cv8 = int2{ packed {bf16(val):hi16, col:lo16},  row }. Single 8B
// scattered store per edge (was 4B+2B to two regions = 2 line touches).
__global__ __launch_bounds__(256) void partition_kernel(const int* __restrict__ rows,
                                                        const int* __restrict__ cols,
                                                        const float* __restrict__ vals,
                                                        const int* __restrict__ bptr_all,
                                                        const int* __restrict__ chunkpre,
                                                        const int* __restrict__ hist,
                                                        int2* __restrict__ cv8) {
    const int r = blockIdx.y;
    rows += (size_t)r * N_EDGES;
    cols += (size_t)r * N_EDGES;
    vals += (size_t)r * N_EDGES;
    cv8  += (size_t)r * N_EDGES;
    const int* bptr = bptr_all + r * (NB + 1);
    const int* hc   = hist     + ((size_t)r * NPBLK + blockIdx.x) * NB;
    const int* cp   = chunkpre + ((size_t)r * NPBLK + blockIdx.x) * NB;
    __shared__ int lh[NB], lptr[NB], lcur[NB], lbase[NB];
    __shared__ int sa[256], sb[256];
    __shared__ int2 st[CHUNK];
    const int tid = threadIdx.x;
    for (int i = tid; i < NB; i += 256) lh[i] = hc[i];
    __syncthreads();
    const int e0 = blockIdx.x * CHUNK;
    const int e1 = min(e0 + CHUNK, N_EDGES);
    const int cnt = e1 - e0;
    const int p0 = (2 * tid < NB) ? lh[2 * tid] : 0;
    const int p1 = (2 * tid + 1 < NB) ? lh[2 * tid + 1] : 0;
    sa[tid] = p0 + p1;
    int* cur = sa;
    int* nxt = sb;
    for (int d = 1; d < 256; d <<= 1) {
        __syncthreads();
        int t = cur[tid];
        if (tid >= d) t += cur[tid - d];
        nxt[tid] = t;
        int* tmp = cur; cur = nxt; nxt = tmp;
    }
    __syncthreads();
    const int pe = cur[tid] - (p0 + p1);
    if (2 * tid < NB)     { lptr[2 * tid] = pe;           lcur[2 * tid] = pe; }
    if (2 * tid + 1 < NB) { lptr[2 * tid + 1] = pe + p0;  lcur[2 * tid + 1] = pe + p0; }
    __syncthreads();
    // int4/float4 edge pass: 4 edges per thread per iteration
    const int nv = cnt >> 2;
    const int4*   rows4 = (const int4*)(rows + e0);
    const int4*   cols4 = (const int4*)(cols + e0);
    const float4* vals4 = (const float4*)(vals + e0);
    for (int i = tid; i < nv; i += 256) {
        const int4   rr = rows4[i];
        const int4   cc = cols4[i];
        const float4 vv = vals4[i];
        int b_, p_;
        b_ = rr.x >> 7; p_ = atomicAdd(&lcur[b_], 1);
        st[p_] = make_int2((int)(((u32)f2bf(vv.x) << 16) | ((u32)cc.x & 0xFFFFu)), rr.x);
        b_ = rr.y >> 7; p_ = atomicAdd(&lcur[b_], 1);
        st[p_] = make_int2((int)(((u32)f2bf(vv.y) << 16) | ((u32)cc.y & 0xFFFFu)), rr.y);
        b_ = rr.z >> 7; p_ = atomicAdd(&lcur[b_], 1);
        st[p_] = make_int2((int)(((u32)f2bf(vv.z) << 16) | ((u32)cc.z & 0xFFFFu)), rr.z);
        b_ = rr.w >> 7; p_ = atomicAdd(&lcur[b_], 1);
        st[p_] = make_int2((int)(((u32)f2bf(vv.w) << 16) | ((u32)cc.w & 0xFFFFu)), rr.w);
    }
    for (int b = tid; b < NB; b += 256) lbase[b] = bptr[b] + cp[b] - lptr[b];
    __syncthreads();
    for (int i = tid; i < cnt; i += 256) {
        const int2 E = st[i];
        const int b = E.y >> 7;
        cv8[lbase[b] + i] = E;
    }
}

// ------- per-bucket CSR: 128-bin counting sort of int2 packed edges ----------
// Single 8B-aligned input stream; pass-1 keys off .y (row id).
__global__ __launch_bounds__(256) void bucket_csr(const int* __restrict__ bptr_all,
                                                  const int2* __restrict__ cv8,
                                                  u32* __restrict__ cv4,
                                                  int* __restrict__ row_ptr) {
    const int r = blockIdx.y;
    const int* bptr = bptr_all + r * (NB + 1);
    cv8     += (size_t)r * N_EDGES;
    cv4     += (size_t)r * N_EDGES;
    row_ptr += r * RP_STRIDE;
    __shared__ int lh[128], lexcl[128], lcur[128];
    __shared__ u32 st[MAXB];
    const int b = blockIdx.x;
    const int s = bptr[b], e1 = bptr[b + 1];
    const int cnt = e1 - s;
    const int tid = threadIdx.x;
    if (tid < 128) lh[tid] = 0;
    __syncthreads();
    for (int i = s + tid; i < e1; i += 256)
        atomicAdd(&lh[cv8[i].y & 127], 1);
    __syncthreads();
    if (tid < 64) {
        const int p0 = lh[2 * tid], p1 = lh[2 * tid + 1];
        int ssum = p0 + p1;
#pragma unroll
        for (int d = 1; d < 64; d <<= 1) {
            const int t = __shfl_up(ssum, d, 64);
            if (tid >= d) ssum += t;
        }
        const int pe = ssum - (p0 + p1);
        lexcl[2 * tid] = pe;          lcur[2 * tid] = pe;
        lexcl[2 * tid + 1] = pe + p0; lcur[2 * tid + 1] = pe + p0;
    }
    __syncthreads();
    for (int i = s + tid; i < e1; i += 256) {
        const int2 E = cv8[i];
        const int lr = E.y & 127;
        const int pos = atomicAdd(&lcur[lr], 1);
        if (pos < MAXB) st[pos] = (u32)E.x;
    }
    __syncthreads();
    const int wb = (cnt < MAXB) ? cnt : MAXB;
    for (int i = tid; i < wb; i += 256) cv4[s + i] = st[i];
    if (tid < 128) {
        const int row = (b << 7) + tid;
        if (row < N_NODES) row_ptr[row] = s + lexcl[tid];
    }
    if (blockIdx.x == 0 && tid == 0) row_ptr[N_NODES] = N_EDGES;
}

// ---------------- SpMM pass 1: y = bf16( filt * (A @ h) ) --------------------
// Round-3 gather scheme (proven best); nt hints on single-use streams.
__global__ __launch_bounds__(256) void spmm1(const int* __restrict__ row_ptr,
                                             const u32* __restrict__ cvp,
                                             const u32* __restrict__ h2,
                                             const float* __restrict__ filt,
                                             u32* __restrict__ y2) {
    const int r = blockIdx.y;
    row_ptr += r * RP_STRIDE;
    cvp     += (size_t)r * N_EDGES;
    filt    += (size_t)r * N_NODES;
    y2      += (size_t)r * (N_NODES * 64);
    const int row = __builtin_amdgcn_readfirstlane(blockIdx.x * 4 + (threadIdx.x >> 6));
    const int lane = threadIdx.x & 63;
    const int half = lane >> 5;
    const int l = lane & 31;
    int e = row_ptr[row];
    const int end = row_ptr[row + 1];
    float a0 = 0.f, a1 = 0.f, a2 = 0.f, a3 = 0.f;
    float b0 = 0.f, b1 = 0.f, b2 = 0.f, b3 = 0.f;
    for (; e + 16 <= end; e += 16) {
        u32 c[16];
#pragma unroll
        for (int i = 0; i < 16; ++i) c[i] = __builtin_nontemporal_load(&cvp[e + i]);
        const u32 u0 = half ? c[1] : c[0];
        const u32 u1 = half ? c[3] : c[2];
        const u32 u2 = half ? c[5] : c[4];
        const u32 u3 = half ? c[7] : c[6];
        const u32 u4 = half ? c[9] : c[8];
        const u32 u5 = half ? c[11] : c[10];
        const u32 u6 = half ? c[13] : c[12];
        const u32 u7 = half ? c[15] : c[14];
        const uint2 g0 = *(const uint2*)(h2 + (u0 & 0xFFFFu) * 64 + 2 * l);
        const uint2 g1 = *(const uint2*)(h2 + (u1 & 0xFFFFu) * 64 + 2 * l);
        const uint2 g2 = *(const uint2*)(h2 + (u2 & 0xFFFFu) * 64 + 2 * l);
        const uint2 g3 = *(const uint2*)(h2 + (u3 & 0xFFFFu) * 64 + 2 * l);
        const uint2 g4 = *(const uint2*)(h2 + (u4 & 0xFFFFu) * 64 + 2 * l);
        const uint2 g5 = *(const uint2*)(h2 + (u5 & 0xFFFFu) * 64 + 2 * l);
        const uint2 g6 = *(const uint2*)(h2 + (u6 & 0xFFFFu) * 64 + 2 * l);
        const uint2 g7 = *(const uint2*)(h2 + (u7 & 0xFFFFu) * 64 + 2 * l);
        const float v0 = __uint_as_float(u0 & 0xFFFF0000u);
        const float v1 = __uint_as_float(u1 & 0xFFFF0000u);
        const float v2 = __uint_as_float(u2 & 0xFFFF0000u);
        const float v3 = __uint_as_float(u3 & 0xFFFF0000u);
        const float v4 = __uint_as_float(u4 & 0xFFFF0000u);
        const float v5 = __uint_as_float(u5 & 0xFFFF0000u);
        const float v6 = __uint_as_float(u6 & 0xFFFF0000u);
        const float v7 = __uint_as_float(u7 & 0xFFFF0000u);
        a0 += v0 * bf_lo(g0.x); a1 += v0 * bf_hi(g0.x);
        a2 += v0 * bf_lo(g0.y); a3 += v0 * bf_hi(g0.y);
        b0 += v1 * bf_lo(g1.x); b1 += v1 * bf_hi(g1.x);
        b2 += v1 * bf_lo(g1.y); b3 += v1 * bf_hi(g1.y);
        a0 += v2 * bf_lo(g2.x); a1 += v2 * bf_hi(g2.x);
        a2 += v2 * bf_lo(g2.y); a3 += v2 * bf_hi(g2.y);
        b0 += v3 * bf_lo(g3.x); b1 += v3 * bf_hi(g3.x);
        b2 += v3 * bf_lo(g3.y); b3 += v3 * bf_hi(g3.y);
        a0 += v4 * bf_lo(g4.x); a1 += v4 * bf_hi(g4.x);
        a2 += v4 * bf_lo(g4.y); a3 += v4 * bf_hi(g4.y);
        b0 += v5 * bf_lo(g5.x); b1 += v5 * bf_hi(g5.x);
        b2 += v5 * bf_lo(g5.y); b3 += v5 * bf_hi(g5.y);
        a0 += v6 * bf_lo(g6.x); a1 += v6 * bf_hi(g6.x);
        a2 += v6 * bf_lo(g6.y); a3 += v6 * bf_hi(g6.y);
        b0 += v7 * bf_lo(g7.x); b1 += v7 * bf_hi(g7.x);
        b2 += v7 * bf_lo(g7.y); b3 += v7 * bf_hi(g7.y);
    }
    for (; e + 8 <= end; e += 8) {
        const u32 c0 = __builtin_nontemporal_load(&cvp[e]);
        const u32 c1 = __builtin_nontemporal_load(&cvp[e + 1]);
        const u32 c2 = __builtin_nontemporal_load(&cvp[e + 2]);
        const u32 c3 = __builtin_nontemporal_load(&cvp[e + 3]);
        const u32 c4 = __builtin_nontemporal_load(&cvp[e + 4]);
        const u32 c5 = __builtin_nontemporal_load(&cvp[e + 5]);
        const u32 c6 = __builtin_nontemporal_load(&cvp[e + 6]);
        const u32 c7 = __builtin_nontemporal_load(&cvp[e + 7]);
        const u32 uA = half ? c1 : c0;
        const u32 uB = half ? c3 : c2;
        const u32 uC = half ? c5 : c4;
        const u32 uD = half ? c7 : c6;
        const uint2 gA = *(const uint2*)(h2 + (uA & 0xFFFFu) * 64 + 2 * l);
        const uint2 gB = *(const uint2*)(h2 + (uB & 0xFFFFu) * 64 + 2 * l);
        const uint2 gC = *(const uint2*)(h2 + (uC & 0xFFFFu) * 64 + 2 * l);
        const uint2 gD = *(const uint2*)(h2 + (uD & 0xFFFFu) * 64 + 2 * l);
        const float vA = __uint_as_float(uA & 0xFFFF0000u);
        const float vB = __uint_as_float(uB & 0xFFFF0000u);
        const float vC = __uint_as_float(uC & 0xFFFF0000u);
        const float vD = __uint_as_float(uD & 0xFFFF0000u);
        a0 += vA * bf_lo(gA.x); a1 += vA * bf_hi(gA.x);
        a2 += vA * bf_lo(gA.y); a3 += vA * bf_hi(gA.y);
        b0 += vB * bf_lo(gB.x); b1 += vB * bf_hi(gB.x);
        b2 += vB * bf_lo(gB.y); b3 += vB * bf_hi(gB.y);
        a0 += vC * bf_lo(gC.x); a1 += vC * bf_hi(gC.x);
        a2 += vC * bf_lo(gC.y); a3 += vC * bf_hi(gC.y);
        b0 += vD * bf_lo(gD.x); b1 += vD * bf_hi(gD.x);
        b2 += vD * bf_lo(gD.y); b3 += vD * bf_hi(gD.y);
    }
    for (; e < end; e += 2) {
        const u32 c0 = __builtin_nontemporal_load(&cvp[e]);
        const u32 c1 = (e + 1 < end) ? __builtin_nontemporal_load(&cvp[e + 1]) : 0u;
        const u32 uA = half ? c1 : c0;
        const uint2 gA = *(const uint2*)(h2 + (uA & 0xFFFFu) * 64 + 2 * l);
        const float vA = __uint_as_float(uA & 0xFFFF0000u);
        a0 += vA * bf_lo(gA.x); a1 += vA * bf_hi(gA.x);
        a2 += vA * bf_lo(gA.y); a3 += vA * bf_hi(gA.y);
    }
    a0 += b0; a1 += b1; a2 += b2; a3 += b3;
    a0 += __shfl_xor(a0, 32, 64);
    a1 += __shfl_xor(a1, 32, 64);
    a2 += __shfl_xor(a2, 32, 64);
    a3 += __shfl_xor(a3, 32, 64);
    const float f = filt[row];
    if (half == 0) {
        u32x2 o;
        o.x = (u32)f2bf(f * a0) | ((u32)f2bf(f * a1) << 16);
        o.y = (u32)f2bf(f * a2) | ((u32)f2bf(f * a3) << 16);
        __builtin_nontemporal_store(o, (u32x2*)(y2 + (size_t)row * 64 + 2 * l));
    }
}

// ---------------- SpMM pass 2 (per-r) ----------------------------------------
template <bool FIRST>
__global__ __launch_bounds__(256) void spmm2(const int* __restrict__ row_ptr,
                                             const u32* __restrict__ cvp,
                                             const u32* __restrict__ y2,
                                             const float* __restrict__ bias,
                                             float* __restrict__ out) {
    const int row = __builtin_amdgcn_readfirstlane(blockIdx.x * 4 + (threadIdx.x >> 6));
    const int lane = threadIdx.x & 63;
    const int half = lane >> 5;
    const int l = lane & 31;
    int e = row_ptr[row];
    const int end = row_ptr[row + 1];
    float a0 = 0.f, a1 = 0.f, a2 = 0.f, a3 = 0.f;
    float b0 = 0.f, b1 = 0.f, b2 = 0.f, b3 = 0.f;
    for (; e + 16 <= end; e += 16) {
        u32 c[16];
#pragma unroll
        for (int i = 0; i < 16; ++i) c[i] = __builtin_nontemporal_load(&cvp[e + i]);
        const u32 u0 = half ? c[1] : c[0];
        const u32 u1 = half ? c[3] : c[2];
        const u32 u2 = half ? c[5] : c[4];
        const u32 u3 = half ? c[7] : c[6];
        const u32 u4 = half ? c[9] : c[8];
        const u32 u5 = half ? c[11] : c[10];
        const u32 u6 = half ? c[13] : c[12];
        const u32 u7 = half ? c[15] : c[14];
        const uint2 g0 = *(const uint2*)(y2 + (u0 & 0xFFFFu) * 64 + 2 * l);
        const uint2 g1 = *(const uint2*)(y2 + (u1 & 0xFFFFu) * 64 + 2 * l);
        const uint2 g2 = *(const uint2*)(y2 + (u2 & 0xFFFFu) * 64 + 2 * l);
        const uint2 g3 = *(const uint2*)(y2 + (u3 & 0xFFFFu) * 64 + 2 * l);
        const uint2 g4 = *(const uint2*)(y2 + (u4 & 0xFFFFu) * 64 + 2 * l);
        const uint2 g5 = *(const uint2*)(y2 + (u5 & 0xFFFFu) * 64 + 2 * l);
        const uint2 g6 = *(const uint2*)(y2 + (u6 & 0xFFFFu) * 64 + 2 * l);
        const uint2 g7 = *(const uint2*)(y2 + (u7 & 0xFFFFu) * 64 + 2 * l);
        const float v0 = __uint_as_float(u0 & 0xFFFF0000u);
        const float v1 = __uint_as_float(u1 & 0xFFFF0000u);
        const float v2 = __uint_as_float(u2 & 0xFFFF0000u);
        const float v3 = __uint_as_float(u3 & 0xFFFF0000u);
        const float v4 = __uint_as_float(u4 & 0xFFFF0000u);
        const float v5 = __uint_as_float(u5 & 0xFFFF0000u);
        const float v6 = __uint_as_float(u6 & 0xFFFF0000u);
        const float v7 = __uint_as_float(u7 & 0xFFFF0000u);
        a0 += v0 * bf_lo(g0.x); a1 += v0 * bf_hi(g0.x);
        a2 += v0 * bf_lo(g0.y); a3 += v0 * bf_hi(g0.y);
        b0 += v1 * bf_lo(g1.x); b1 += v1 * bf_hi(g1.x);
        b2 += v1 * bf_lo(g1.y); b3 += v1 * bf_hi(g1.y);
        a0 += v2 * bf_lo(g2.x); a1 += v2 * bf_hi(g2.x);
        a2 += v2 * bf_lo(g2.y); a3 += v2 * bf_hi(g2.y);
        b0 += v3 * bf_lo(g3.x); b1 += v3 * bf_hi(g3.x);
        b2 += v3 * bf_lo(g3.y); b3 += v3 * bf_hi(g3.y);
        a0 += v4 * bf_lo(g4.x); a1 += v4 * bf_hi(g4.x);
        a2 += v4 * bf_lo(g4.y); a3 += v4 * bf_hi(g4.y);
        b0 += v5 * bf_lo(g5.x); b1 += v5 * bf_hi(g5.x);
        b2 += v5 * bf_lo(g5.y); b3 += v5 * bf_hi(g5.y);
        a0 += v6 * bf_lo(g6.x); a1 += v6 * bf_hi(g6.x);
        a2 += v6 * bf_lo(g6.y); a3 += v6 * bf_hi(g6.y);
        b0 += v7 * bf_lo(g7.x); b1 += v7 * bf_hi(g7.x);
        b2 += v7 * bf_lo(g7.y); b3 += v7 * bf_hi(g7.y);
    }
    for (; e + 8 <= end; e += 8) {
        const u32 c0 = __builtin_nontemporal_load(&cvp[e]);
        const u32 c1 = __builtin_nontemporal_load(&cvp[e + 1]);
        const u32 c2 = __builtin_nontemporal_load(&cvp[e + 2]);
        const u32 c3 = __builtin_nontemporal_load(&cvp[e + 3]);
        const u32 c4 = __builtin_nontemporal_load(&cvp[e + 4]);
        const u32 c5 = __builtin_nontemporal_load(&cvp[e + 5]);
        const u32 c6 = __builtin_nontemporal_load(&cvp[e + 6]);
        const u32 c7 = __builtin_nontemporal_load(&cvp[e + 7]);
        const u32 uA = half ? c1 : c0;
        const u32 uB = half ? c3 : c2;
        const u32 uC = half ? c5 : c4;
        const u32 uD = half ? c7 : c6;
        const uint2 gA = *(const uint2*)(y2 + (uA & 0xFFFFu) * 64 + 2 * l);
        const uint2 gB = *(const uint2*)(y2 + (uB & 0xFFFFu) * 64 + 2 * l);
        const uint2 gC = *(const uint2*)(y2 + (uC & 0xFFFFu) * 64 + 2 * l);
        const uint2 gD = *(const uint2*)(y2 + (uD & 0xFFFFu) * 64 + 2 * l);
        const float vA = __uint_as_float(uA & 0xFFFF0000u);
        const float vB = __uint_as_float(uB & 0xFFFF0000u);
        const float vC = __uint_as_float(uC & 0xFFFF0000u);
        const float vD = __uint_as_float(uD & 0xFFFF0000u);
        a0 += vA * bf_lo(gA.x); a1 += vA * bf_hi(gA.x);
        a2 += vA * bf_lo(gA.y); a3 += vA * bf_hi(gA.y);
        b0 += vB * bf_lo(gB.x); b1 += vB * bf_hi(gB.x);
        b2 += vB * bf_lo(gB.y); b3 += vB * bf_hi(gB.y);
        a0 += vC * bf_lo(gC.x); a1 += vC * bf_hi(gC.x);
        a2 += vC * bf_lo(gC.y); a3 += vC * bf_hi(gC.y);
        b0 += vD * bf_lo(gD.x); b1 += vD * bf_hi(gD.x);
        b2 += vD * bf_lo(gD.y); b3 += vD * bf_hi(gD.y);
    }
    for (; e < end; e += 2) {
        const u32 c0 = __builtin_nontemporal_load(&cvp[e]);
        const u32 c1 = (e + 1 < end) ? __builtin_nontemporal_load(&cvp[e + 1]) : 0u;
        const u32 uA = half ? c1 : c0;
        const uint2 gA = *(const uint2*)(y2 + (uA & 0xFFFFu) * 64 + 2 * l);
        const float vA = __uint_as_float(uA & 0xFFFF0000u);
        a0 += vA * bf_lo(gA.x); a1 += vA * bf_hi(gA.x);
        a2 += vA * bf_lo(gA.y); a3 += vA * bf_hi(gA.y);
    }
    a0 += b0; a1 += b1; a2 += b2; a3 += b3;
    a0 += __shfl_xor(a0, 32, 64);
    a1 += __shfl_xor(a1, 32, 64);
    a2 += __shfl_xor(a2, 32, 64);
    a3 += __shfl_xor(a3, 32, 64);
    if (half == 0) {
        float* op = out + (size_t)row * D + 4 * l;
        if (FIRST) {
            const float4 bb = *(const float4*)(bias + 4 * l);
            f32x4 o = {a0 + bb.x, a1 + bb.y, a2 + bb.z, a3 + bb.w};
            __builtin_nontemporal_store(o, (f32x4*)op);
        } else {
            const f32x4 cc = __builtin_nontemporal_load((const f32x4*)op);
            f32x4 o = {cc.x + a0, cc.y + a1, cc.z + a2, cc.w + a3};
            __builtin_nontemporal_store(o, (f32x4*)op);
        }
    }
}

extern "C" void kernel_launch(void* const* d_in, const int* in_sizes, int n_in,
                              void* d_out, int out_size, void* d_ws, size_t ws_size,
                              hipStream_t stream) {
    const float* x    = (const float*)d_in[0];  // [N,128]
    const float* vals = (const float*)d_in[1];  // [R,E]
    const float* W    = (const float*)d_in[2];  // [128,128]
    const float* filt = (const float*)d_in[3];  // [R*N,1]
    const float* bias = (const float*)d_in[4];  // [128]
    const int*   rows = (const int*)d_in[5];    // [R,E]
    const int*   cols = (const int*)d_in[6];    // [R,E]
    float* out = (float*)d_out;                 // [N,128]

    char* ws = (char*)d_ws;
    // Layout (<= 90,419,968 B, proven available):
    //   [0, 12.8M)        h bf16 [N][128]
    //   [12.8M, 64M)      cv8 int2 [R][E] (51.2 MB), aliased by
    //                     y2 bf16 [R][N][128] (cv8 dead before spmm1 writes y2)
    //   [64M, 89.6M)      cv4 u32 [R][E]  (alias: hist+cpre, 4.9 MB, dead
    //                     before bucket_csr writes cv4)
    //   [89.6M, ...)      rp, cnt, bptr
    u16*  h      = (u16*)(ws);
    int2* cv8    = (int2*)(ws + 12800000);
    u32*  y2     = (u32*)(ws + 12800000);          // alias of cv8
    u32*  cv4    = (u32*)(ws + 64000000);
    int*  hist   = (int*)(ws + 64000000);          // alias of cv4 region
    int*  cpre   = (int*)(ws + 66446096);          // alias of cv4 region
    int*  rp     = (int*)(ws + 89600000);          // 4 x RP_STRIDE ints
    int*  cnt4   = (int*)(ws + 90400512);          // 4*NB ints
    int*  bptr4  = (int*)(ws + 90406768);          // 4*(NB+1) ints

    bucket_hist_all<<<dim3(NPBLK, R_WAV), 256, 0, stream>>>(rows, hist);
    chunk_scan<<<dim3(NB, R_WAV), 512, 0, stream>>>(hist, cpre, cnt4);
    scan_buckets_all<<<R_WAV, 512, 0, stream>>>(cnt4, bptr4);
    partition_kernel<<<dim3(NPBLK, R_WAV), 256, 0, stream>>>(rows, cols, vals,
                                                             bptr4, cpre, hist, cv8);
    bucket_csr<<<dim3(NB, R_WAV), 256, 0, stream>>>(bptr4, cv8, cv4, rp);

    gemm_xw<<<N_NODES / 16, 512, 0, stream>>>(x, W, h);

    spmm1<<<dim3(N_NODES / 4, R_WAV), 256, 0, stream>>>(rp, cv4, (const u32*)h,
                                                        filt, y2);
    for (int r = 0; r < R_WAV; ++r) {
        const int* rp_r  = rp + r * RP_STRIDE;
        const u32* cv4_r = cv4 + (size_t)r * N_EDGES;
        const u32* y2_r  = y2 + (size_t)r * (N_NODES * 64);
        if (r == 0)
            spmm2<true><<<N_NODES / 4, 256, 0, stream>>>(rp_r, cv4_r, y2_r, bias, out);
        else
            spmm2<false><<<N_NODES / 4, 256, 0, stream>>>(rp_r, cv4_r, y2_r, bias, out);
    }
}